// Round 1
// baseline (20905.571 us; speedup 1.0000x reference)
//
#include <hip/hip_runtime.h>
#include <cstddef>
#include <cstdint>

// Problem constants
#define kB 32
#define kT 2048
#define kIn 512
#define kH 256
#define kBeta 0.85f
#define kThr 1.0f

// Fused-kernel layout: blocks [0, N_SCAN) = scan (one per batch),
// blocks [N_SCAN, N_SCAN+N_GEMM) = GEMM tiles (256x256, t-major order).
#define N_SCAN kB
#define N_GEMM (kB * 8)        // 32 b x 8 t_tiles (256 rows each)
#define FLAGS_PER_B 8
#define TBURST 8

// GEMM tile config: 256x256 tile, BK=16, 1024 threads, 8x8 micro-tile.
#define GBM 256
#define GBK 16
#define GLDA 260               // +4 pad: conflict-free transposed staging
#define SMEM_FLOATS (2 * GBK * GLDA)   // 8320 floats = 33.3 KB (>= scan's 8.3 KB)

__device__ __forceinline__ void wait_flag(int* f) {
    // acquire/agent: later proj loads must see the producer XCD's stores
    while (__hip_atomic_load(f, __ATOMIC_ACQUIRE, __HIP_MEMORY_SCOPE_AGENT) == 0) {
        __builtin_amdgcn_s_sleep(2);
    }
}

// ---------------------------------------------------------------------------
// GEMM body: proj tile = x(256xK) @ W_in^T(Kx256) + b_in, then publish flag.
// Unchanged from previous rounds (bit-identical proj).
// ---------------------------------------------------------------------------
__device__ void gemm_body(const float* __restrict__ A,
                          const float* __restrict__ W,
                          const float* __restrict__ bias,
                          float* __restrict__ P,
                          int* flags, int gid, float* smem)
{
    float* As = smem;
    float* Bs = smem + GBK * GLDA;
    const int tid = threadIdx.x;
    const int b  = gid & 31;          // t-major tile order: all b at t_tile 0 first
    const int tt = gid >> 5;          // 0..7
    const int bm = b * kT + tt * GBM; // row offset in flattened (B*T)
    const int tx = tid & 31;
    const int ty = tid >> 5;          // 0..31

    float acc[8][8];
#pragma unroll
    for (int i = 0; i < 8; ++i)
#pragma unroll
        for (int j = 0; j < 8; ++j) acc[i][j] = 0.f;

    const int r = tid >> 2, kc = (tid & 3) << 2;

    for (int kb = 0; kb < kIn; kb += GBK) {
        const float4 av = *reinterpret_cast<const float4*>(A + (size_t)(bm + r) * kIn + kb + kc);
        const float4 bv = *reinterpret_cast<const float4*>(W + (size_t)r * kIn + kb + kc);
        __syncthreads();   // previous iteration's LDS reads done
        As[(kc + 0) * GLDA + r] = av.x;
        As[(kc + 1) * GLDA + r] = av.y;
        As[(kc + 2) * GLDA + r] = av.z;
        As[(kc + 3) * GLDA + r] = av.w;
        Bs[(kc + 0) * GLDA + r] = bv.x;
        Bs[(kc + 1) * GLDA + r] = bv.y;
        Bs[(kc + 2) * GLDA + r] = bv.z;
        Bs[(kc + 3) * GLDA + r] = bv.w;
        __syncthreads();

#pragma unroll
        for (int k = 0; k < GBK; ++k) {
            const float4 aa0 = *reinterpret_cast<const float4*>(&As[k * GLDA + ty * 4]);
            const float4 aa1 = *reinterpret_cast<const float4*>(&As[k * GLDA + ty * 4 + 128]);
            const float4 bb0 = *reinterpret_cast<const float4*>(&Bs[k * GLDA + tx * 4]);
            const float4 bb1 = *reinterpret_cast<const float4*>(&Bs[k * GLDA + tx * 4 + 128]);
            const float av8[8] = {aa0.x, aa0.y, aa0.z, aa0.w, aa1.x, aa1.y, aa1.z, aa1.w};
            const float bv8[8] = {bb0.x, bb0.y, bb0.z, bb0.w, bb1.x, bb1.y, bb1.z, bb1.w};
#pragma unroll
            for (int i = 0; i < 8; ++i)
#pragma unroll
                for (int j = 0; j < 8; ++j)
                    acc[i][j] = fmaf(av8[i], bv8[j], acc[i][j]);
        }
    }

    const float4 bl = *reinterpret_cast<const float4*>(bias + tx * 4);
    const float4 bh = *reinterpret_cast<const float4*>(bias + tx * 4 + 128);
#pragma unroll
    for (int i = 0; i < 8; ++i) {
        const int m = bm + ty * 4 + (i & 3) + ((i >> 2) << 7);
        float4 o0, o1;
        o0.x = acc[i][0] + bl.x; o0.y = acc[i][1] + bl.y;
        o0.z = acc[i][2] + bl.z; o0.w = acc[i][3] + bl.w;
        o1.x = acc[i][4] + bh.x; o1.y = acc[i][5] + bh.y;
        o1.z = acc[i][6] + bh.z; o1.w = acc[i][7] + bh.w;
        *reinterpret_cast<float4*>(P + (size_t)m * kH + tx * 4) = o0;
        *reinterpret_cast<float4*>(P + (size_t)m * kH + tx * 4 + 128) = o1;
    }

    __syncthreads();   // all stores executed block-wide
    if (flags && tid == 0) {
        __threadfence();                                  // device-scope release
        atomicAdd(flags + b * FLAGS_PER_B + tt, 1);       // publish (b, tt) ready
    }
}

// ---------------------------------------------------------------------------
// Scan, round 7: 4-wave no-reduce design. Each owner thread (h = tid < 256)
// holds its full V row in 256 VGPRs and computes the entire recurrent dot
// locally; per-step cross-wave exchange is just 4 ballot words through a
// double-buffered 64 B LDS mask -> ONE barrier per step (was two + a 16-way
// LDS partial reduction). Per-bit coefficients come from a 256-entry x 8
// float {0,1} LUT in LDS (broadcast ds_read_b128, branchless, no per-bit
// SALU). Chunk-sum order, reduction tree, and membrane update are copied
// verbatim from the verified round-6 kernel -> bit-identical output.
// MYW = this wave's mask-word index; its own word bypasses LDS (ballot reg).
// ---------------------------------------------------------------------------
template<int MYW>
__device__ void scan_owner_loop(float* __restrict__ base,
                                const float* __restrict__ V,
                                const float br,
                                int* bflags,
                                const float* lut,
                                unsigned long long* smask,
                                const int h)
{
    // one-time: this h's V row into 256 VGPRs (Vr[k] = V[h][k])
    float Vr[256];
    {
        const float4* vp = reinterpret_cast<const float4*>(V + (size_t)h * kH);
#pragma unroll
        for (int c4 = 0; c4 < 64; ++c4) {
            const float4 v = vp[c4];
            Vr[c4 * 4 + 0] = v.x; Vr[c4 * 4 + 1] = v.y;
            Vr[c4 * 4 + 2] = v.z; Vr[c4 * 4 + 3] = v.w;
        }
    }

    float mem = 0.f, spk = 0.f;
    // shift registers: current-burst proj, next-burst proj, spike outbox
    float p0, p1, p2, p3, p4, p5, p6, p7;
    float q0, q1, q2, q3, q4, q5, q6, q7;
    float o0, o1, o2, o3, o4, o5, o6, o7;
    q0=q1=q2=q3=q4=q5=q6=q7 = 0.f;
    o0=o1=o2=o3=o4=o5=o6=o7 = 0.f;

    if (bflags) wait_flag(bflags + 0);     // proj tile (b, t<256) ready
    p0 = base[(size_t)0 * kH]; p1 = base[(size_t)1 * kH];
    p2 = base[(size_t)2 * kH]; p3 = base[(size_t)3 * kH];
    p4 = base[(size_t)4 * kH]; p5 = base[(size_t)5 * kH];
    p6 = base[(size_t)6 * kH]; p7 = base[(size_t)7 * kH];

    unsigned long long myword = 0ull;      // this wave's mask word (spk=0 at t=0)

    __syncthreads();                       // matches non-owner initial barrier

    for (int t = 0; t < kT; ++t) {
        // ---- vmem burst (1 step in 8, issued at step-top so the barrier's
        //      vmcnt drain is mostly retired by step end): store last 8
        //      spikes + prefetch next 8 proj rows.
        if ((t & 7) == 0) {
            if (t > 0) {
                float* sb = base + (size_t)(t - 8) * kH;
                sb[(size_t)0 * kH] = o0; sb[(size_t)1 * kH] = o1;
                sb[(size_t)2 * kH] = o2; sb[(size_t)3 * kH] = o3;
                sb[(size_t)4 * kH] = o4; sb[(size_t)5 * kH] = o5;
                sb[(size_t)6 * kH] = o6; sb[(size_t)7 * kH] = o7;
            }
            const int nb = (t >> 3) + 1;
            if (bflags && nb < (kT / TBURST) && (nb & 31) == 0)
                wait_flag(bflags + (nb >> 5));             // next 256-step tile
            const int rb = nb << 3;
            const int r0i = (rb + 0 < kT) ? rb + 0 : kT - 1;   // clamp (harmless)
            const int r1i = (rb + 1 < kT) ? rb + 1 : kT - 1;
            const int r2i = (rb + 2 < kT) ? rb + 2 : kT - 1;
            const int r3i = (rb + 3 < kT) ? rb + 3 : kT - 1;
            const int r4i = (rb + 4 < kT) ? rb + 4 : kT - 1;
            const int r5i = (rb + 5 < kT) ? rb + 5 : kT - 1;
            const int r6i = (rb + 6 < kT) ? rb + 6 : kT - 1;
            const int r7i = (rb + 7 < kT) ? rb + 7 : kT - 1;
            q0 = base[(size_t)r0i * kH]; q1 = base[(size_t)r1i * kH];
            q2 = base[(size_t)r2i * kH]; q3 = base[(size_t)r3i * kH];
            q4 = base[(size_t)r4i * kH]; q5 = base[(size_t)r5i * kH];
            q6 = base[(size_t)r6i * kH]; q7 = base[(size_t)r7i * kH];
        }

        // ---- mask: own word from ballot register, other 3 via LDS
        const int rs = t & 1;
        unsigned long long mw0, mw1, mw2, mw3;
        {
            const ulonglong2 a = *reinterpret_cast<const ulonglong2*>(smask + rs * 4);
            const ulonglong2 c = *reinterpret_cast<const ulonglong2*>(smask + rs * 4 + 2);
            mw0 = a.x; mw1 = a.y; mw2 = c.x; mw3 = c.y;
        }
        if (MYW == 0) mw0 = myword;
        if (MYW == 1) mw1 = myword;
        if (MYW == 2) mw2 = myword;
        if (MYW == 3) mw3 = myword;

        uint32_t mwu[8];
        mwu[0] = __builtin_amdgcn_readfirstlane((uint32_t)mw0);
        mwu[1] = __builtin_amdgcn_readfirstlane((uint32_t)(mw0 >> 32));
        mwu[2] = __builtin_amdgcn_readfirstlane((uint32_t)mw1);
        mwu[3] = __builtin_amdgcn_readfirstlane((uint32_t)(mw1 >> 32));
        mwu[4] = __builtin_amdgcn_readfirstlane((uint32_t)mw2);
        mwu[5] = __builtin_amdgcn_readfirstlane((uint32_t)(mw2 >> 32));
        mwu[6] = __builtin_amdgcn_readfirstlane((uint32_t)mw3);
        mwu[7] = __builtin_amdgcn_readfirstlane((uint32_t)(mw3 >> 32));

        // ---- full recurrent dot, thread-local. Chunk c = 16 sequential fma
        // (k ascending), coefficients exactly 0.0/1.0 from the byte LUT:
        // bit-identical to round-6's per-chunk sums (fma(0,v,a)==a exactly).
        float cs[16];
#pragma unroll
        for (int c = 0; c < 16; ++c) {
            const uint32_t ch = (mwu[c >> 1] >> ((c & 1) * 16)) & 0xFFFFu;
            const float* lo = lut + ((ch & 0xFFu) << 3);
            const float* hi = lut + ((ch >> 8) << 3);
            const float4 fa = *reinterpret_cast<const float4*>(lo);
            const float4 fb = *reinterpret_cast<const float4*>(lo + 4);
            const float4 fc = *reinterpret_cast<const float4*>(hi);
            const float4 fd = *reinterpret_cast<const float4*>(hi + 4);
            float a = 0.f;
            a = fmaf(fa.x, Vr[c * 16 +  0], a); a = fmaf(fa.y, Vr[c * 16 +  1], a);
            a = fmaf(fa.z, Vr[c * 16 +  2], a); a = fmaf(fa.w, Vr[c * 16 +  3], a);
            a = fmaf(fb.x, Vr[c * 16 +  4], a); a = fmaf(fb.y, Vr[c * 16 +  5], a);
            a = fmaf(fb.z, Vr[c * 16 +  6], a); a = fmaf(fb.w, Vr[c * 16 +  7], a);
            a = fmaf(fc.x, Vr[c * 16 +  8], a); a = fmaf(fc.y, Vr[c * 16 +  9], a);
            a = fmaf(fc.z, Vr[c * 16 + 10], a); a = fmaf(fc.w, Vr[c * 16 + 11], a);
            a = fmaf(fd.x, Vr[c * 16 + 12], a); a = fmaf(fd.y, Vr[c * 16 + 13], a);
            a = fmaf(fd.z, Vr[c * 16 + 14], a); a = fmaf(fd.w, Vr[c * 16 + 15], a);
            cs[c] = a;
        }

        // identical 16-leaf reduction tree as round 6's owner reduce
        const float r0 = (cs[0] + cs[1]) + (cs[2] + cs[3]);
        const float r1 = (cs[4] + cs[5]) + (cs[6] + cs[7]);
        const float r2 = (cs[8] + cs[9]) + (cs[10] + cs[11]);
        const float r3 = (cs[12] + cs[13]) + (cs[14] + cs[15]);
        const float rec = ((r0 + r1) + (r2 + r3)) + br;

        const float p = p0;
        float m2;
        {
#pragma clang fp contract(off)
            const float input_ = p + spk;   // combined = proj + spk
            m2 = kBeta * mem;               // reference op order
            m2 = m2 + input_;
            m2 = m2 + rec;
            m2 = m2 - spk * kThr;           // reset == spk_prev exactly
        }
        const bool fire = (m2 > kThr);
        const float ns = fire ? 1.0f : 0.0f;
        const unsigned long long bm = __ballot(fire);
        if ((threadIdx.x & 63) == 0) smask[(rs ^ 1) * 4 + MYW] = bm;
        mem = m2;
        spk = ns;
        myword = bm;

        // shift registers
        if ((t & 7) == 7) {
            p0 = q0; p1 = q1; p2 = q2; p3 = q3;
            p4 = q4; p5 = q5; p6 = q6; p7 = q7;
        } else {
            p0 = p1; p1 = p2; p2 = p3; p3 = p4; p4 = p5; p5 = p6; p6 = p7;
        }
        o0 = o1; o1 = o2; o2 = o3; o3 = o4; o4 = o5; o5 = o6; o6 = o7; o7 = ns;

        __syncthreads();   // the ONE barrier: new mask words visible
    }

    // final burst of spikes (t = kT-8 .. kT-1)
    {
        float* sb = base + (size_t)(kT - 8) * kH;
        sb[(size_t)0 * kH] = o0; sb[(size_t)1 * kH] = o1;
        sb[(size_t)2 * kH] = o2; sb[(size_t)3 * kH] = o3;
        sb[(size_t)4 * kH] = o4; sb[(size_t)5 * kH] = o5;
        sb[(size_t)6 * kH] = o6; sb[(size_t)7 * kH] = o7;
    }
}

// ---------------------------------------------------------------------------
__device__ void scan_body(float* __restrict__ PO,
                          const float* __restrict__ V,
                          const float* __restrict__ brec,
                          int* flags, float* smem)
{
    float* lut = smem;                      // 256 entries x 8 floats = 8 KB
    unsigned long long* smask =
        reinterpret_cast<unsigned long long*>(smem + 2048);  // 2 slots x 4 u64

    const int b = blockIdx.x;
    const int tid = threadIdx.x;

    // one-time LUT init: entry e, lane j -> exact 0.0f / 1.0f
    if (tid < 256) {
#pragma unroll
        for (int j = 0; j < 8; ++j)
            lut[tid * 8 + j] = (float)((tid >> j) & 1);
    }
    if (tid < 8) smask[tid] = 0ull;

    int* bflags = flags ? (flags + b * FLAGS_PER_B) : nullptr;

    if (tid < kH) {
        float* base = PO + (size_t)b * (size_t)kT * kH + tid;
        const float br = brec[tid];
        switch (tid >> 6) {
            case 0:  scan_owner_loop<0>(base, V, br, bflags, lut, smask, tid); break;
            case 1:  scan_owner_loop<1>(base, V, br, bflags, lut, smask, tid); break;
            case 2:  scan_owner_loop<2>(base, V, br, bflags, lut, smask, tid); break;
            default: scan_owner_loop<3>(base, V, br, bflags, lut, smask, tid); break;
        }
    } else {
        // non-owner waves: barrier companions only (wave-uniform divergence)
        __syncthreads();                    // initial
        for (int t = 0; t < kT; ++t) __syncthreads();
    }
}

// ---------------------------------------------------------------------------
__global__ void __launch_bounds__(1024, 4)
fused(const float* __restrict__ x, const float* __restrict__ W,
      const float* __restrict__ b_in, const float* __restrict__ V,
      const float* __restrict__ b_rec, float* __restrict__ PO,
      int* flags, int n_scan)
{
    __shared__ __align__(16) float smem[SMEM_FLOATS];
    if ((int)blockIdx.x < n_scan) {
        scan_body(PO, V, b_rec, flags, smem);
    } else {
        gemm_body(x, W, b_in, PO, flags, (int)blockIdx.x - n_scan, smem);
    }
}

// ---------------------------------------------------------------------------
extern "C" void kernel_launch(void* const* d_in, const int* in_sizes, int n_in,
                              void* d_out, int out_size, void* d_ws, size_t ws_size,
                              hipStream_t stream) {
    const float* x     = (const float*)d_in[0];
    const float* W_in  = (const float*)d_in[1];
    const float* b_in  = (const float*)d_in[2];
    const float* V     = (const float*)d_in[3];
    const float* b_rec = (const float*)d_in[4];
    float* out = (float*)d_out;

    const size_t flag_bytes = (size_t)N_SCAN * FLAGS_PER_B * sizeof(int);
    if (ws_size >= flag_bytes) {
        int* flags = (int*)d_ws;
        hipMemsetAsync(flags, 0, flag_bytes, stream);   // ws is poisoned 0xAA
        fused<<<N_SCAN + N_GEMM, 1024, 0, stream>>>(x, W_in, b_in, V, b_rec,
                                                    out, flags, N_SCAN);
    } else {
        // fallback: sequential (no flags) — GEMM pass, then scan pass
        fused<<<N_GEMM, 1024, 0, stream>>>(x, W_in, b_in, V, b_rec, out, nullptr, 0);
        fused<<<N_SCAN, 1024, 0, stream>>>(x, W_in, b_in, V, b_rec, out, nullptr, N_SCAN);
    }
}

// Round 2
// 4313.165 us; speedup vs baseline: 4.8469x; 4.8469x over previous
//
#include <hip/hip_runtime.h>
#include <cstddef>
#include <cstdint>

// Problem constants
#define kB 32
#define kT 2048
#define kIn 512
#define kH 256
#define kBeta 0.85f
#define kThr 1.0f

// Fused-kernel layout: blocks [0, N_SCAN) = scan (one per batch),
// blocks [N_SCAN, N_SCAN+N_GEMM) = GEMM tiles (128x128, t-chunk-major order).
// 256-thread blocks so the scan path may hold 256+ VGPRs (1 wave/SIMD).
#define N_SCAN kB
#define N_GEMM 1024            // 8 chunks x 32 b x 4 subtiles (2 tt x 2 ch)
#define FLAGS_PER_B 8
#define TBURST 8

// GEMM tile config: 128x128 tile, BK=16, 256 threads, 8x8 micro-tile.
#define GBK 16
#define GLDA 132               // +4 pad: conflict-free transposed staging
#define SMEM_FLOATS (2 * GBK * GLDA)   // 4224 floats = 16.9 KB (>= scan's 2 KB)

__device__ __forceinline__ void wait_flag4(int* f) {
    // each 256-t chunk is produced by 4 GEMM tiles (2 tt x 2 ch)
    while (__hip_atomic_load(f, __ATOMIC_ACQUIRE, __HIP_MEMORY_SCOPE_AGENT) < 4) {
        __builtin_amdgcn_s_sleep(2);
    }
}

// ---------------------------------------------------------------------------
// GEMM body: proj tile = x(128xK) @ W_in^T(Kx128) + b_in, then publish flag.
// Per-element k-summation: one fma chain, k strictly ascending 0..511, bias
// added once at the end -> bit-identical to all previous verified rounds.
// ---------------------------------------------------------------------------
__device__ void gemm_body(const float* __restrict__ A,
                          const float* __restrict__ W,
                          const float* __restrict__ bias,
                          float* __restrict__ P,
                          int* flags, int gid, float* smem)
{
    float* As = smem;
    float* Bs = smem + GBK * GLDA;
    const int tid = threadIdx.x;
    const int c   = gid >> 7;            // t-chunk 0..7 (256 timesteps each)
    const int rr  = gid & 127;
    const int b   = rr >> 2;             // batch
    const int sub = rr & 3;
    const int tt  = c * 2 + (sub >> 1);  // 128-row tile index 0..15
    const int ch  = sub & 1;             // output column half
    const int bm  = b * kT + tt * 128;   // row offset in flattened (B*T)
    const int hb  = ch * 128;            // col offset in H

    const int tx = tid & 15;             // 0..15
    const int ty = tid >> 4;             // 0..15

    float acc[8][8];
#pragma unroll
    for (int i = 0; i < 8; ++i)
#pragma unroll
        for (int j = 0; j < 8; ++j) acc[i][j] = 0.f;

    const int r = tid >> 1, kc = (tid & 1) * 8;   // 2 threads cover 16 k's/row

    for (int kb = 0; kb < kIn; kb += GBK) {
        const float4 a0 = *reinterpret_cast<const float4*>(A + (size_t)(bm + r) * kIn + kb + kc);
        const float4 a1 = *reinterpret_cast<const float4*>(A + (size_t)(bm + r) * kIn + kb + kc + 4);
        const float4 w0 = *reinterpret_cast<const float4*>(W + (size_t)(hb + r) * kIn + kb + kc);
        const float4 w1 = *reinterpret_cast<const float4*>(W + (size_t)(hb + r) * kIn + kb + kc + 4);
        __syncthreads();   // previous iteration's LDS reads done
        As[(kc + 0) * GLDA + r] = a0.x;
        As[(kc + 1) * GLDA + r] = a0.y;
        As[(kc + 2) * GLDA + r] = a0.z;
        As[(kc + 3) * GLDA + r] = a0.w;
        As[(kc + 4) * GLDA + r] = a1.x;
        As[(kc + 5) * GLDA + r] = a1.y;
        As[(kc + 6) * GLDA + r] = a1.z;
        As[(kc + 7) * GLDA + r] = a1.w;
        Bs[(kc + 0) * GLDA + r] = w0.x;
        Bs[(kc + 1) * GLDA + r] = w0.y;
        Bs[(kc + 2) * GLDA + r] = w0.z;
        Bs[(kc + 3) * GLDA + r] = w0.w;
        Bs[(kc + 4) * GLDA + r] = w1.x;
        Bs[(kc + 5) * GLDA + r] = w1.y;
        Bs[(kc + 6) * GLDA + r] = w1.z;
        Bs[(kc + 7) * GLDA + r] = w1.w;
        __syncthreads();

#pragma unroll
        for (int k = 0; k < GBK; ++k) {
            const float4 aa0 = *reinterpret_cast<const float4*>(&As[k * GLDA + ty * 4]);
            const float4 aa1 = *reinterpret_cast<const float4*>(&As[k * GLDA + ty * 4 + 64]);
            const float4 bb0 = *reinterpret_cast<const float4*>(&Bs[k * GLDA + tx * 4]);
            const float4 bb1 = *reinterpret_cast<const float4*>(&Bs[k * GLDA + tx * 4 + 64]);
            const float av8[8] = {aa0.x, aa0.y, aa0.z, aa0.w, aa1.x, aa1.y, aa1.z, aa1.w};
            const float bv8[8] = {bb0.x, bb0.y, bb0.z, bb0.w, bb1.x, bb1.y, bb1.z, bb1.w};
#pragma unroll
            for (int i = 0; i < 8; ++i)
#pragma unroll
                for (int j = 0; j < 8; ++j)
                    acc[i][j] = fmaf(av8[i], bv8[j], acc[i][j]);
        }
    }

    const float4 bl = *reinterpret_cast<const float4*>(bias + hb + tx * 4);
    const float4 bh = *reinterpret_cast<const float4*>(bias + hb + tx * 4 + 64);
#pragma unroll
    for (int i = 0; i < 8; ++i) {
        const int m = bm + ty * 4 + (i & 3) + ((i >> 2) << 6);
        float4 o0, o1;
        o0.x = acc[i][0] + bl.x; o0.y = acc[i][1] + bl.y;
        o0.z = acc[i][2] + bl.z; o0.w = acc[i][3] + bl.w;
        o1.x = acc[i][4] + bh.x; o1.y = acc[i][5] + bh.y;
        o1.z = acc[i][6] + bh.z; o1.w = acc[i][7] + bh.w;
        *reinterpret_cast<float4*>(P + (size_t)m * kH + hb + tx * 4) = o0;
        *reinterpret_cast<float4*>(P + (size_t)m * kH + hb + tx * 4 + 64) = o1;
    }

    __syncthreads();   // all stores executed block-wide
    if (flags && tid == 0) {
        __threadfence();                                  // device-scope release
        atomicAdd(flags + b * FLAGS_PER_B + c, 1);        // publish 1 of 4 for (b,c)
    }
}

// ---------------------------------------------------------------------------
// Scan, round 8: 4-wave (256-thread) no-reduce design. Thread h holds its
// full V row in 256 VGPRs (legal now: 256-thread block -> 1 wave/SIMD -> up
// to 512 VGPRs; round 7's 1024-thread block capped at 128 and spilled).
// Spikes are exchanged as FLOATS through a double-buffered 256-float LDS
// vector: write own spike (1 ds_write), read all coefficients as broadcast
// float4s (64 uniform-address ds_read_b128) -- no ballot/readfirstlane/LUT.
// Coefficients are exactly 0.0f/1.0f; chunk fma chains (k ascending, 16 per
// chunk), the 16-leaf reduction tree, and the contract-off membrane update
// are verbatim from the absmax-0.0-verified round-7 numerics.
// ---------------------------------------------------------------------------
__device__ void scan_body(float* __restrict__ PO,
                          const float* __restrict__ V,
                          const float* __restrict__ brec,
                          int* flags, float* smem)
{
    const int b = blockIdx.x;
    const int tid = threadIdx.x;           // == h, 0..255
    float* base = PO + (size_t)b * (size_t)kT * kH + tid;

    // one-time: this h's V row into 256 VGPRs (Vr[k] = V[h][k])
    float Vr[256];
    {
        const float4* vp = reinterpret_cast<const float4*>(V + (size_t)tid * kH);
#pragma unroll
        for (int c4 = 0; c4 < 64; ++c4) {
            const float4 v = vp[c4];
            Vr[c4 * 4 + 0] = v.x; Vr[c4 * 4 + 1] = v.y;
            Vr[c4 * 4 + 2] = v.z; Vr[c4 * 4 + 3] = v.w;
        }
    }

    const float br = brec[tid];
    float mem = 0.f, spk = 0.f;

    // double-buffered spike vector: slot s at smem + s*256 (both init 0)
    smem[tid] = 0.f;
    smem[256 + tid] = 0.f;

    int* bflags = flags ? (flags + b * FLAGS_PER_B) : nullptr;

    // shift registers: current-burst proj, next-burst proj, spike outbox
    float p0, p1, p2, p3, p4, p5, p6, p7;
    float q0, q1, q2, q3, q4, q5, q6, q7;
    float o0, o1, o2, o3, o4, o5, o6, o7;
    q0=q1=q2=q3=q4=q5=q6=q7 = 0.f;
    o0=o1=o2=o3=o4=o5=o6=o7 = 0.f;

    if (bflags) wait_flag4(bflags + 0);    // proj chunk (b, t<256) ready
    p0 = base[(size_t)0 * kH]; p1 = base[(size_t)1 * kH];
    p2 = base[(size_t)2 * kH]; p3 = base[(size_t)3 * kH];
    p4 = base[(size_t)4 * kH]; p5 = base[(size_t)5 * kH];
    p6 = base[(size_t)6 * kH]; p7 = base[(size_t)7 * kH];

    __syncthreads();                       // spike buffers (zeros) visible

    for (int t = 0; t < kT; ++t) {
        // ---- vmem burst (1 step in 8, issued at step-top): store last 8
        //      spikes + prefetch next 8 proj rows. Steps in between are
        //      vmem-clean so barrier drains are cheap.
        if ((t & 7) == 0) {
            if (t > 0) {
                float* sb = base + (size_t)(t - 8) * kH;
                sb[(size_t)0 * kH] = o0; sb[(size_t)1 * kH] = o1;
                sb[(size_t)2 * kH] = o2; sb[(size_t)3 * kH] = o3;
                sb[(size_t)4 * kH] = o4; sb[(size_t)5 * kH] = o5;
                sb[(size_t)6 * kH] = o6; sb[(size_t)7 * kH] = o7;
            }
            const int nb = (t >> 3) + 1;
            if (bflags && nb < (kT / TBURST) && (nb & 31) == 0)
                wait_flag4(bflags + (nb >> 5));            // next 256-step chunk
            const int rb = nb << 3;
            const int r0i = (rb + 0 < kT) ? rb + 0 : kT - 1;   // clamp (harmless)
            const int r1i = (rb + 1 < kT) ? rb + 1 : kT - 1;
            const int r2i = (rb + 2 < kT) ? rb + 2 : kT - 1;
            const int r3i = (rb + 3 < kT) ? rb + 3 : kT - 1;
            const int r4i = (rb + 4 < kT) ? rb + 4 : kT - 1;
            const int r5i = (rb + 5 < kT) ? rb + 5 : kT - 1;
            const int r6i = (rb + 6 < kT) ? rb + 6 : kT - 1;
            const int r7i = (rb + 7 < kT) ? rb + 7 : kT - 1;
            q0 = base[(size_t)r0i * kH]; q1 = base[(size_t)r1i * kH];
            q2 = base[(size_t)r2i * kH]; q3 = base[(size_t)r3i * kH];
            q4 = base[(size_t)r4i * kH]; q5 = base[(size_t)r5i * kH];
            q6 = base[(size_t)r6i * kH]; q7 = base[(size_t)r7i * kH];
        }

        // ---- full recurrent dot, thread-local. Chunk c = 16 sequential fma
        // (k ascending); coefficients are the exact 0.0/1.0 spike floats.
        const float* sb = smem + (t & 1) * 256;
        float cs[16];
#pragma unroll
        for (int c = 0; c < 16; ++c) {
            const float4 f0 = *reinterpret_cast<const float4*>(sb + c * 16);
            const float4 f1 = *reinterpret_cast<const float4*>(sb + c * 16 + 4);
            const float4 f2 = *reinterpret_cast<const float4*>(sb + c * 16 + 8);
            const float4 f3 = *reinterpret_cast<const float4*>(sb + c * 16 + 12);
            float a = 0.f;
            a = fmaf(f0.x, Vr[c * 16 +  0], a); a = fmaf(f0.y, Vr[c * 16 +  1], a);
            a = fmaf(f0.z, Vr[c * 16 +  2], a); a = fmaf(f0.w, Vr[c * 16 +  3], a);
            a = fmaf(f1.x, Vr[c * 16 +  4], a); a = fmaf(f1.y, Vr[c * 16 +  5], a);
            a = fmaf(f1.z, Vr[c * 16 +  6], a); a = fmaf(f1.w, Vr[c * 16 +  7], a);
            a = fmaf(f2.x, Vr[c * 16 +  8], a); a = fmaf(f2.y, Vr[c * 16 +  9], a);
            a = fmaf(f2.z, Vr[c * 16 + 10], a); a = fmaf(f2.w, Vr[c * 16 + 11], a);
            a = fmaf(f3.x, Vr[c * 16 + 12], a); a = fmaf(f3.y, Vr[c * 16 + 13], a);
            a = fmaf(f3.z, Vr[c * 16 + 14], a); a = fmaf(f3.w, Vr[c * 16 + 15], a);
            cs[c] = a;
        }

        // identical 16-leaf reduction tree as verified rounds
        const float r0 = (cs[0] + cs[1]) + (cs[2] + cs[3]);
        const float r1 = (cs[4] + cs[5]) + (cs[6] + cs[7]);
        const float r2 = (cs[8] + cs[9]) + (cs[10] + cs[11]);
        const float r3 = (cs[12] + cs[13]) + (cs[14] + cs[15]);
        const float rec = ((r0 + r1) + (r2 + r3)) + br;

        const float p = p0;
        float m2;
        {
#pragma clang fp contract(off)
            const float input_ = p + spk;   // combined = proj + spk
            m2 = kBeta * mem;               // reference op order
            m2 = m2 + input_;
            m2 = m2 + rec;
            m2 = m2 - spk * kThr;           // reset == spk_prev exactly
        }
        const bool fire = (m2 > kThr);
        const float ns = fire ? 1.0f : 0.0f;
        smem[((t & 1) ^ 1) * 256 + tid] = ns;   // publish next-step coefficient
        mem = m2;
        spk = ns;

        // shift registers
        if ((t & 7) == 7) {
            p0 = q0; p1 = q1; p2 = q2; p3 = q3;
            p4 = q4; p5 = q5; p6 = q6; p7 = q7;
        } else {
            p0 = p1; p1 = p2; p2 = p3; p3 = p4; p4 = p5; p5 = p6; p6 = p7;
        }
        o0 = o1; o1 = o2; o2 = o3; o3 = o4; o4 = o5; o5 = o6; o6 = o7; o7 = ns;

        __syncthreads();   // the ONE barrier: new spike vector visible
    }

    // final burst of spikes (t = kT-8 .. kT-1)
    {
        float* sb2 = base + (size_t)(kT - 8) * kH;
        sb2[(size_t)0 * kH] = o0; sb2[(size_t)1 * kH] = o1;
        sb2[(size_t)2 * kH] = o2; sb2[(size_t)3 * kH] = o3;
        sb2[(size_t)4 * kH] = o4; sb2[(size_t)5 * kH] = o5;
        sb2[(size_t)6 * kH] = o6; sb2[(size_t)7 * kH] = o7;
    }
}

// ---------------------------------------------------------------------------
__global__ void __launch_bounds__(256, 1)
fused(const float* __restrict__ x, const float* __restrict__ W,
      const float* __restrict__ b_in, const float* __restrict__ V,
      const float* __restrict__ b_rec, float* __restrict__ PO,
      int* flags, int n_scan)
{
    __shared__ __align__(16) float smem[SMEM_FLOATS];
    if ((int)blockIdx.x < n_scan) {
        scan_body(PO, V, b_rec, flags, smem);
    } else {
        gemm_body(x, W, b_in, PO, flags, (int)blockIdx.x - n_scan, smem);
    }
}

// ---------------------------------------------------------------------------
extern "C" void kernel_launch(void* const* d_in, const int* in_sizes, int n_in,
                              void* d_out, int out_size, void* d_ws, size_t ws_size,
                              hipStream_t stream) {
    const float* x     = (const float*)d_in[0];
    const float* W_in  = (const float*)d_in[1];
    const float* b_in  = (const float*)d_in[2];
    const float* V     = (const float*)d_in[3];
    const float* b_rec = (const float*)d_in[4];
    float* out = (float*)d_out;

    const size_t flag_bytes = (size_t)N_SCAN * FLAGS_PER_B * sizeof(int);
    if (ws_size >= flag_bytes) {
        int* flags = (int*)d_ws;
        hipMemsetAsync(flags, 0, flag_bytes, stream);   // ws is poisoned 0xAA
        fused<<<N_SCAN + N_GEMM, 256, 0, stream>>>(x, W_in, b_in, V, b_rec,
                                                   out, flags, N_SCAN);
    } else {
        // fallback: sequential (no flags) — GEMM pass, then scan pass
        fused<<<N_GEMM, 256, 0, stream>>>(x, W_in, b_in, V, b_rec, out, nullptr, 0);
        fused<<<N_SCAN, 256, 0, stream>>>(x, W_in, b_in, V, b_rec, out, nullptr, N_SCAN);
    }
}

// Round 3
// 2168.666 us; speedup vs baseline: 9.6398x; 1.9889x over previous
//
#include <hip/hip_runtime.h>
#include <cstddef>
#include <cstdint>

// Problem constants
#define kB 32
#define kT 2048
#define kIn 512
#define kH 256
#define kBeta 0.85f
#define kThr 1.0f

// Fused-kernel layout: blocks [0, N_SCAN) = scan (one per batch),
// blocks [N_SCAN, N_SCAN+N_GEMM) = GEMM tiles (128x256, chunk-major order).
// 512-thread blocks: scan thread (h, half) holds half a V row (128 VGPRs),
// safely under the 256 arch-VGPR ISA cap (round 8's full-row/thread spilled).
#define N_SCAN kB
#define N_GEMM 512             // 8 chunks x 32 b x 2 row-subtiles (128 t each)
#define FLAGS_PER_B 8
#define TBURST 8

// GEMM tile config: 128 rows x 256 cols (full H), BK=16, 512 threads,
// 8x8 micro-tile on a 32x16 thread grid.
#define GBK 16
#define GLDA 132               // A-stage stride (+4 pad)
#define GLDB 260               // W-stage stride (+4 pad)
#define SMEM_FLOATS (GBK * GLDA + GBK * GLDB)   // 6272 floats = 25.1 KB

__device__ __forceinline__ void wait_flag2(int* f) {
    // each 256-t chunk is produced by 2 GEMM tiles (128 rows each)
    while (__hip_atomic_load(f, __ATOMIC_ACQUIRE, __HIP_MEMORY_SCOPE_AGENT) < 2) {
        __builtin_amdgcn_s_sleep(2);
    }
}

// ---------------------------------------------------------------------------
// GEMM body: proj tile = x(128xK) @ W_in^T(Kx256) + b_in, then publish flag.
// Per-element k-summation: one fma chain, k strictly ascending 0..511, bias
// added once at the end -> bit-identical to all previous verified rounds.
// ---------------------------------------------------------------------------
__device__ void gemm_body(const float* __restrict__ A,
                          const float* __restrict__ W,
                          const float* __restrict__ bias,
                          float* __restrict__ P,
                          int* flags, int gid, float* smem)
{
    float* As = smem;                  // [GBK][GLDA]  (transposed: As[k][row])
    float* Bs = smem + GBK * GLDA;     // [GBK][GLDB]  (transposed: Bs[k][col])
    const int tid = threadIdx.x;       // 0..511
    const int c   = gid >> 6;          // t-chunk 0..7 (256 timesteps each)
    const int rem = gid & 63;
    const int b   = rem >> 1;          // batch 0..31
    const int sub = rem & 1;           // row half of the chunk
    const int tt  = c * 2 + sub;       // 128-row tile index 0..15
    const int bm  = b * kT + tt * 128; // row offset in flattened (B*T)

    const int tx = tid & 31;           // col group: cols tx*4 (+128)
    const int ty = tid >> 5;           // row group 0..15

    float acc[8][8];
#pragma unroll
    for (int i = 0; i < 8; ++i)
#pragma unroll
        for (int j = 0; j < 8; ++j) acc[i][j] = 0.f;

    const int rA = tid >> 2, kcA = (tid & 3) << 2;   // A: 128 rows x 4 k-floats
    const int rW = tid >> 1, kcW = (tid & 1) << 3;   // W: 256 rows x 8 k-floats

    for (int kb = 0; kb < kIn; kb += GBK) {
        const float4 a0 = *reinterpret_cast<const float4*>(A + (size_t)(bm + rA) * kIn + kb + kcA);
        const float4 w0 = *reinterpret_cast<const float4*>(W + (size_t)rW * kIn + kb + kcW);
        const float4 w1 = *reinterpret_cast<const float4*>(W + (size_t)rW * kIn + kb + kcW + 4);
        __syncthreads();   // previous iteration's LDS reads done
        As[(kcA + 0) * GLDA + rA] = a0.x;
        As[(kcA + 1) * GLDA + rA] = a0.y;
        As[(kcA + 2) * GLDA + rA] = a0.z;
        As[(kcA + 3) * GLDA + rA] = a0.w;
        Bs[(kcW + 0) * GLDB + rW] = w0.x;
        Bs[(kcW + 1) * GLDB + rW] = w0.y;
        Bs[(kcW + 2) * GLDB + rW] = w0.z;
        Bs[(kcW + 3) * GLDB + rW] = w0.w;
        Bs[(kcW + 4) * GLDB + rW] = w1.x;
        Bs[(kcW + 5) * GLDB + rW] = w1.y;
        Bs[(kcW + 6) * GLDB + rW] = w1.z;
        Bs[(kcW + 7) * GLDB + rW] = w1.w;
        __syncthreads();

#pragma unroll
        for (int k = 0; k < GBK; ++k) {
            const float4 aa0 = *reinterpret_cast<const float4*>(&As[k * GLDA + ty * 4]);
            const float4 aa1 = *reinterpret_cast<const float4*>(&As[k * GLDA + ty * 4 + 64]);
            const float4 bb0 = *reinterpret_cast<const float4*>(&Bs[k * GLDB + tx * 4]);
            const float4 bb1 = *reinterpret_cast<const float4*>(&Bs[k * GLDB + tx * 4 + 128]);
            const float av8[8] = {aa0.x, aa0.y, aa0.z, aa0.w, aa1.x, aa1.y, aa1.z, aa1.w};
            const float bv8[8] = {bb0.x, bb0.y, bb0.z, bb0.w, bb1.x, bb1.y, bb1.z, bb1.w};
#pragma unroll
            for (int i = 0; i < 8; ++i)
#pragma unroll
                for (int j = 0; j < 8; ++j)
                    acc[i][j] = fmaf(av8[i], bv8[j], acc[i][j]);
        }
    }

    const float4 bl = *reinterpret_cast<const float4*>(bias + tx * 4);
    const float4 bh = *reinterpret_cast<const float4*>(bias + tx * 4 + 128);
#pragma unroll
    for (int i = 0; i < 8; ++i) {
        const int m = bm + ty * 4 + (i & 3) + ((i >> 2) << 6);
        float4 o0, o1;
        o0.x = acc[i][0] + bl.x; o0.y = acc[i][1] + bl.y;
        o0.z = acc[i][2] + bl.z; o0.w = acc[i][3] + bl.w;
        o1.x = acc[i][4] + bh.x; o1.y = acc[i][5] + bh.y;
        o1.z = acc[i][6] + bh.z; o1.w = acc[i][7] + bh.w;
        *reinterpret_cast<float4*>(P + (size_t)m * kH + tx * 4) = o0;
        *reinterpret_cast<float4*>(P + (size_t)m * kH + tx * 4 + 128) = o1;
    }

    __syncthreads();   // all stores executed block-wide
    if (flags && tid == 0) {
        __threadfence();                                  // device-scope release
        atomicAdd(flags + b * FLAGS_PER_B + c, 1);        // publish 1 of 2 for (b,c)
    }
}

// ---------------------------------------------------------------------------
// Scan, round 9: 512-thread half-row split. Thread (h, half) holds
// Vr[128] = V[h][half*128..+127] (fits the 256 arch-VGPR cap; round 8's
// full row could not). Per step each thread computes its half-dot from the
// broadcast 0/1 spike floats (double-buffered 256-float LDS vector, verified
// absmax 0.0 in round 8); half1 writes one partial float; owners (half0)
// finish rec = (low + high) + br -- exactly the verified 16-leaf tree
// ((r0+r1)+(r2+r3))+br -- then do the membrane update verbatim.
// LDS: spikes 2x256 floats @ smem[0..511], partials 256 floats @ smem[512..].
// ---------------------------------------------------------------------------
__device__ void scan_body(float* __restrict__ PO,
                          const float* __restrict__ V,
                          const float* __restrict__ brec,
                          int* flags, float* smem)
{
    const int b = blockIdx.x;
    const int tid = threadIdx.x;       // 0..511
    const int h = tid & 255;
    const int half = tid >> 8;         // 0 = owner (k<128), 1 = high half
    float* base = PO + (size_t)b * (size_t)kT * kH + h;
    float* part = smem + 512;

    // one-time: this thread's half V row into 128 VGPRs
    float Vr[128];
    {
        const float4* vp = reinterpret_cast<const float4*>(V + (size_t)h * kH + half * 128);
#pragma unroll
        for (int c4 = 0; c4 < 32; ++c4) {
            const float4 v = vp[c4];
            Vr[c4 * 4 + 0] = v.x; Vr[c4 * 4 + 1] = v.y;
            Vr[c4 * 4 + 2] = v.z; Vr[c4 * 4 + 3] = v.w;
        }
    }

    const float br = (half == 0) ? brec[h] : 0.f;
    float mem = 0.f, spk = 0.f;

    smem[tid] = 0.f;                   // zeroes both spike slots (2x256)

    int* bflags = flags ? (flags + b * FLAGS_PER_B) : nullptr;

    // owner-only shift registers: cur-burst proj, next-burst proj, spike outbox
    float p0, p1, p2, p3, p4, p5, p6, p7;
    float q0, q1, q2, q3, q4, q5, q6, q7;
    float o0, o1, o2, o3, o4, o5, o6, o7;
    p0=p1=p2=p3=p4=p5=p6=p7 = 0.f;
    q0=q1=q2=q3=q4=q5=q6=q7 = 0.f;
    o0=o1=o2=o3=o4=o5=o6=o7 = 0.f;

    if (half == 0) {
        if (bflags) wait_flag2(bflags + 0);    // proj chunk (b, t<256) ready
        p0 = base[(size_t)0 * kH]; p1 = base[(size_t)1 * kH];
        p2 = base[(size_t)2 * kH]; p3 = base[(size_t)3 * kH];
        p4 = base[(size_t)4 * kH]; p5 = base[(size_t)5 * kH];
        p6 = base[(size_t)6 * kH]; p7 = base[(size_t)7 * kH];
    }

    __syncthreads();                   // spike zeros visible

    for (int t = 0; t < kT; ++t) {
        // ---- vmem burst (owners, 1 step in 8, issued at step-top): store
        //      last 8 spikes + prefetch next 8 proj rows.
        if (half == 0 && (t & 7) == 0) {
            if (t > 0) {
                float* sg = base + (size_t)(t - 8) * kH;
                sg[(size_t)0 * kH] = o0; sg[(size_t)1 * kH] = o1;
                sg[(size_t)2 * kH] = o2; sg[(size_t)3 * kH] = o3;
                sg[(size_t)4 * kH] = o4; sg[(size_t)5 * kH] = o5;
                sg[(size_t)6 * kH] = o6; sg[(size_t)7 * kH] = o7;
            }
            const int nb = (t >> 3) + 1;
            if (bflags && nb < (kT / TBURST) && (nb & 31) == 0)
                wait_flag2(bflags + (nb >> 5));            // next 256-step chunk
            const int rb = nb << 3;
            const int r0i = (rb + 0 < kT) ? rb + 0 : kT - 1;   // clamp (harmless)
            const int r1i = (rb + 1 < kT) ? rb + 1 : kT - 1;
            const int r2i = (rb + 2 < kT) ? rb + 2 : kT - 1;
            const int r3i = (rb + 3 < kT) ? rb + 3 : kT - 1;
            const int r4i = (rb + 4 < kT) ? rb + 4 : kT - 1;
            const int r5i = (rb + 5 < kT) ? rb + 5 : kT - 1;
            const int r6i = (rb + 6 < kT) ? rb + 6 : kT - 1;
            const int r7i = (rb + 7 < kT) ? rb + 7 : kT - 1;
            q0 = base[(size_t)r0i * kH]; q1 = base[(size_t)r1i * kH];
            q2 = base[(size_t)r2i * kH]; q3 = base[(size_t)r3i * kH];
            q4 = base[(size_t)r4i * kH]; q5 = base[(size_t)r5i * kH];
            q6 = base[(size_t)r6i * kH]; q7 = base[(size_t)r7i * kH];
        }

        // ---- half-dot: 8 chunk-chains of 16 fma (k ascending); coefficients
        // are the exact 0.0/1.0 spike floats (broadcast reads).
        const float* sb = smem + (t & 1) * 256 + half * 128;
        float cs[8];
#pragma unroll
        for (int c = 0; c < 8; ++c) {
            const float4 f0 = *reinterpret_cast<const float4*>(sb + c * 16);
            const float4 f1 = *reinterpret_cast<const float4*>(sb + c * 16 + 4);
            const float4 f2 = *reinterpret_cast<const float4*>(sb + c * 16 + 8);
            const float4 f3 = *reinterpret_cast<const float4*>(sb + c * 16 + 12);
            float a = 0.f;
            a = fmaf(f0.x, Vr[c * 16 +  0], a); a = fmaf(f0.y, Vr[c * 16 +  1], a);
            a = fmaf(f0.z, Vr[c * 16 +  2], a); a = fmaf(f0.w, Vr[c * 16 +  3], a);
            a = fmaf(f1.x, Vr[c * 16 +  4], a); a = fmaf(f1.y, Vr[c * 16 +  5], a);
            a = fmaf(f1.z, Vr[c * 16 +  6], a); a = fmaf(f1.w, Vr[c * 16 +  7], a);
            a = fmaf(f2.x, Vr[c * 16 +  8], a); a = fmaf(f2.y, Vr[c * 16 +  9], a);
            a = fmaf(f2.z, Vr[c * 16 + 10], a); a = fmaf(f2.w, Vr[c * 16 + 11], a);
            a = fmaf(f3.x, Vr[c * 16 + 12], a); a = fmaf(f3.y, Vr[c * 16 + 13], a);
            a = fmaf(f3.z, Vr[c * 16 + 14], a); a = fmaf(f3.w, Vr[c * 16 + 15], a);
            cs[c] = a;
        }
        // pairwise halves of the verified 16-leaf tree
        const float ra = (cs[0] + cs[1]) + (cs[2] + cs[3]);
        const float rb2 = (cs[4] + cs[5]) + (cs[6] + cs[7]);
        const float halfsum = ra + rb2;    // half0: (r0+r1); half1: (r2+r3)

        if (half == 1) part[h] = halfsum;

        __syncthreads();   // barrier A: high partials visible

        if (half == 0) {
            const float rec = (halfsum + part[h]) + br;   // ((r0+r1)+(r2+r3))+br
            const float p = p0;
            float m2;
            {
#pragma clang fp contract(off)
                const float input_ = p + spk;   // combined = proj + spk
                m2 = kBeta * mem;               // reference op order
                m2 = m2 + input_;
                m2 = m2 + rec;
                m2 = m2 - spk * kThr;           // reset == spk_prev exactly
            }
            const bool fire = (m2 > kThr);
            const float ns = fire ? 1.0f : 0.0f;
            smem[((t & 1) ^ 1) * 256 + h] = ns;   // publish next-step coefficient
            mem = m2;
            spk = ns;

            // shift registers
            if ((t & 7) == 7) {
                p0 = q0; p1 = q1; p2 = q2; p3 = q3;
                p4 = q4; p5 = q5; p6 = q6; p7 = q7;
            } else {
                p0 = p1; p1 = p2; p2 = p3; p3 = p4; p4 = p5; p5 = p6; p6 = p7;
            }
            o0 = o1; o1 = o2; o2 = o3; o3 = o4; o4 = o5; o5 = o6; o6 = o7; o7 = ns;
        }

        __syncthreads();   // barrier B: spike vector + partial-reuse safe
    }

    // final burst of spikes (t = kT-8 .. kT-1)
    if (half == 0) {
        float* sg = base + (size_t)(kT - 8) * kH;
        sg[(size_t)0 * kH] = o0; sg[(size_t)1 * kH] = o1;
        sg[(size_t)2 * kH] = o2; sg[(size_t)3 * kH] = o3;
        sg[(size_t)4 * kH] = o4; sg[(size_t)5 * kH] = o5;
        sg[(size_t)6 * kH] = o6; sg[(size_t)7 * kH] = o7;
    }
}

// ---------------------------------------------------------------------------
__global__ void __launch_bounds__(512, 2)
fused(const float* __restrict__ x, const float* __restrict__ W,
      const float* __restrict__ b_in, const float* __restrict__ V,
      const float* __restrict__ b_rec, float* __restrict__ PO,
      int* flags, int n_scan)
{
    __shared__ __align__(16) float smem[SMEM_FLOATS];
    if ((int)blockIdx.x < n_scan) {
        scan_body(PO, V, b_rec, flags, smem);
    } else {
        gemm_body(x, W, b_in, PO, flags, (int)blockIdx.x - n_scan, smem);
    }
}

// ---------------------------------------------------------------------------
extern "C" void kernel_launch(void* const* d_in, const int* in_sizes, int n_in,
                              void* d_out, int out_size, void* d_ws, size_t ws_size,
                              hipStream_t stream) {
    const float* x     = (const float*)d_in[0];
    const float* W_in  = (const float*)d_in[1];
    const float* b_in  = (const float*)d_in[2];
    const float* V     = (const float*)d_in[3];
    const float* b_rec = (const float*)d_in[4];
    float* out = (float*)d_out;

    const size_t flag_bytes = (size_t)N_SCAN * FLAGS_PER_B * sizeof(int);
    if (ws_size >= flag_bytes) {
        int* flags = (int*)d_ws;
        hipMemsetAsync(flags, 0, flag_bytes, stream);   // ws is poisoned 0xAA
        fused<<<N_SCAN + N_GEMM, 512, 0, stream>>>(x, W_in, b_in, V, b_rec,
                                                   out, flags, N_SCAN);
    } else {
        // fallback: sequential (no flags) — GEMM pass, then scan pass
        fused<<<N_GEMM, 512, 0, stream>>>(x, W_in, b_in, V, b_rec, out, nullptr, 0);
        fused<<<N_SCAN, 512, 0, stream>>>(x, W_in, b_in, V, b_rec, out, nullptr, N_SCAN);
    }
}

// Round 4
// 2126.492 us; speedup vs baseline: 9.8310x; 1.0198x over previous
//
#include <hip/hip_runtime.h>
#include <cstddef>
#include <cstdint>

// Problem constants
#define kB 32
#define kT 2048
#define kIn 512
#define kH 256
#define kBeta 0.85f
#define kThr 1.0f

// Fused-kernel layout: blocks [0, N_SCAN) = scan (one per batch),
// blocks [N_SCAN, N_SCAN+N_GEMM) = GEMM tiles (256x256, t-major order).
// 1024-thread blocks; scan thread (h, quarter) holds a quarter V row
// (64 VGPRs) -> total ~120 arch VGPRs, under the 128 cap at 4 waves/SIMD.
// (R8 full row spilled to scratch; R9 half row spilled to AGPRs.)
#define N_SCAN kB
#define N_GEMM (kB * 8)        // 32 b x 8 t_tiles (256 rows each)
#define FLAGS_PER_B 8
#define TBURST 8

// GEMM tile config: 256x256 tile, BK=16, 1024 threads, 8x8 micro-tile.
#define GBM 256
#define GBK 16
#define GLDA 260               // +4 pad: conflict-free transposed staging
#define SMEM_FLOATS (2 * GBK * GLDA)   // 8320 floats = 33.3 KB (>= scan's 5.1 KB)

__device__ __forceinline__ void wait_flag(int* f) {
    // acquire/agent: later proj loads must see the producer XCD's stores
    while (__hip_atomic_load(f, __ATOMIC_ACQUIRE, __HIP_MEMORY_SCOPE_AGENT) == 0) {
        __builtin_amdgcn_s_sleep(2);
    }
}

// ---------------------------------------------------------------------------
// GEMM body: proj tile = x(256xK) @ W_in^T(Kx256) + b_in, then publish flag.
// Verbatim from the verified round-6 kernel (bit-identical proj).
// ---------------------------------------------------------------------------
__device__ void gemm_body(const float* __restrict__ A,
                          const float* __restrict__ W,
                          const float* __restrict__ bias,
                          float* __restrict__ P,
                          int* flags, int gid, float* smem)
{
    float* As = smem;
    float* Bs = smem + GBK * GLDA;
    const int tid = threadIdx.x;
    const int b  = gid & 31;          // t-major tile order: all b at t_tile 0 first
    const int tt = gid >> 5;          // 0..7
    const int bm = b * kT + tt * GBM; // row offset in flattened (B*T)
    const int tx = tid & 31;
    const int ty = tid >> 5;          // 0..31

    float acc[8][8];
#pragma unroll
    for (int i = 0; i < 8; ++i)
#pragma unroll
        for (int j = 0; j < 8; ++j) acc[i][j] = 0.f;

    const int r = tid >> 2, kc = (tid & 3) << 2;

    for (int kb = 0; kb < kIn; kb += GBK) {
        const float4 av = *reinterpret_cast<const float4*>(A + (size_t)(bm + r) * kIn + kb + kc);
        const float4 bv = *reinterpret_cast<const float4*>(W + (size_t)r * kIn + kb + kc);
        __syncthreads();   // previous iteration's LDS reads done
        As[(kc + 0) * GLDA + r] = av.x;
        As[(kc + 1) * GLDA + r] = av.y;
        As[(kc + 2) * GLDA + r] = av.z;
        As[(kc + 3) * GLDA + r] = av.w;
        Bs[(kc + 0) * GLDA + r] = bv.x;
        Bs[(kc + 1) * GLDA + r] = bv.y;
        Bs[(kc + 2) * GLDA + r] = bv.z;
        Bs[(kc + 3) * GLDA + r] = bv.w;
        __syncthreads();

#pragma unroll
        for (int k = 0; k < GBK; ++k) {
            const float4 aa0 = *reinterpret_cast<const float4*>(&As[k * GLDA + ty * 4]);
            const float4 aa1 = *reinterpret_cast<const float4*>(&As[k * GLDA + ty * 4 + 128]);
            const float4 bb0 = *reinterpret_cast<const float4*>(&Bs[k * GLDA + tx * 4]);
            const float4 bb1 = *reinterpret_cast<const float4*>(&Bs[k * GLDA + tx * 4 + 128]);
            const float av8[8] = {aa0.x, aa0.y, aa0.z, aa0.w, aa1.x, aa1.y, aa1.z, aa1.w};
            const float bv8[8] = {bb0.x, bb0.y, bb0.z, bb0.w, bb1.x, bb1.y, bb1.z, bb1.w};
#pragma unroll
            for (int i = 0; i < 8; ++i)
#pragma unroll
                for (int j = 0; j < 8; ++j)
                    acc[i][j] = fmaf(av8[i], bv8[j], acc[i][j]);
        }
    }

    const float4 bl = *reinterpret_cast<const float4*>(bias + tx * 4);
    const float4 bh = *reinterpret_cast<const float4*>(bias + tx * 4 + 128);
#pragma unroll
    for (int i = 0; i < 8; ++i) {
        const int m = bm + ty * 4 + (i & 3) + ((i >> 2) << 7);
        float4 o0, o1;
        o0.x = acc[i][0] + bl.x; o0.y = acc[i][1] + bl.y;
        o0.z = acc[i][2] + bl.z; o0.w = acc[i][3] + bl.w;
        o1.x = acc[i][4] + bh.x; o1.y = acc[i][5] + bh.y;
        o1.z = acc[i][6] + bh.z; o1.w = acc[i][7] + bh.w;
        *reinterpret_cast<float4*>(P + (size_t)m * kH + tx * 4) = o0;
        *reinterpret_cast<float4*>(P + (size_t)m * kH + tx * 4 + 128) = o1;
    }

    __syncthreads();   // all stores executed block-wide
    if (flags && tid == 0) {
        __threadfence();                                  // device-scope release
        atomicAdd(flags + b * FLAGS_PER_B + tt, 1);       // publish (b, tt) ready
    }
}

// ---------------------------------------------------------------------------
// Scan, round 10: 1024-thread quarter-row split. Thread (h, qtr) holds
// Vr[64] = V[h][qtr*64 .. +63] -- ~120 arch VGPRs total, fits the 128 cap
// at 4 waves/SIMD with zero AGPR/scratch traffic (R9's half-row did not).
// Per step each thread computes its quarter-dot from the broadcast 0/1
// spike floats (double-buffered 256-float LDS vector, absmax-0.0-verified
// in rounds 8/9); quarters 1..3 write one partial each; owners (qtr 0)
// finish rec = ((r0+r1)+(r2+r3))+br -- exactly the verified 16-leaf tree --
// then do the membrane update verbatim. Two barriers/step.
// LDS: spikes 2x256 @ smem[0..511], partials 3x256 @ smem[512..1279].
// ---------------------------------------------------------------------------
__device__ void scan_body(float* __restrict__ PO,
                          const float* __restrict__ V,
                          const float* __restrict__ brec,
                          int* flags, float* smem)
{
    const int b = blockIdx.x;
    const int tid = threadIdx.x;       // 0..1023
    const int h = tid & 255;
    const int qtr = tid >> 8;          // 0..3: k range [qtr*64, qtr*64+64)
    float* base = PO + (size_t)b * (size_t)kT * kH + h;
    float* part = smem + 512;          // part[(qtr-1)*256 + h]

    // one-time: this thread's quarter V row into 64 VGPRs
    float Vr[64];
    {
        const float4* vp = reinterpret_cast<const float4*>(V + (size_t)h * kH + qtr * 64);
#pragma unroll
        for (int c4 = 0; c4 < 16; ++c4) {
            const float4 v = vp[c4];
            Vr[c4 * 4 + 0] = v.x; Vr[c4 * 4 + 1] = v.y;
            Vr[c4 * 4 + 2] = v.z; Vr[c4 * 4 + 3] = v.w;
        }
    }

    const float br = (qtr == 0) ? brec[h] : 0.f;
    float mem = 0.f, spk = 0.f;

    if (tid < 512) smem[tid] = 0.f;    // zero both spike slots (2x256)

    int* bflags = flags ? (flags + b * FLAGS_PER_B) : nullptr;

    // owner-only shift registers: cur-burst proj, next-burst proj, spike outbox
    float p0, p1, p2, p3, p4, p5, p6, p7;
    float q0, q1, q2, q3, q4, q5, q6, q7;
    float o0, o1, o2, o3, o4, o5, o6, o7;
    p0=p1=p2=p3=p4=p5=p6=p7 = 0.f;
    q0=q1=q2=q3=q4=q5=q6=q7 = 0.f;
    o0=o1=o2=o3=o4=o5=o6=o7 = 0.f;

    if (qtr == 0) {
        if (bflags) wait_flag(bflags + 0);     // proj tile (b, t<256) ready
        p0 = base[(size_t)0 * kH]; p1 = base[(size_t)1 * kH];
        p2 = base[(size_t)2 * kH]; p3 = base[(size_t)3 * kH];
        p4 = base[(size_t)4 * kH]; p5 = base[(size_t)5 * kH];
        p6 = base[(size_t)6 * kH]; p7 = base[(size_t)7 * kH];
    }

    __syncthreads();                   // spike zeros visible

    for (int t = 0; t < kT; ++t) {
        // ---- vmem burst (owners, 1 step in 8, issued at step-top): store
        //      last 8 spikes + prefetch next 8 proj rows. Steps in between
        //      are vmem-clean so barrier drains are cheap.
        if (qtr == 0 && (t & 7) == 0) {
            if (t > 0) {
                float* sg = base + (size_t)(t - 8) * kH;
                sg[(size_t)0 * kH] = o0; sg[(size_t)1 * kH] = o1;
                sg[(size_t)2 * kH] = o2; sg[(size_t)3 * kH] = o3;
                sg[(size_t)4 * kH] = o4; sg[(size_t)5 * kH] = o5;
                sg[(size_t)6 * kH] = o6; sg[(size_t)7 * kH] = o7;
            }
            const int nb = (t >> 3) + 1;
            if (bflags && nb < (kT / TBURST) && (nb & 31) == 0)
                wait_flag(bflags + (nb >> 5));             // next 256-step tile
            const int rb = nb << 3;
            const int r0i = (rb + 0 < kT) ? rb + 0 : kT - 1;   // clamp (harmless)
            const int r1i = (rb + 1 < kT) ? rb + 1 : kT - 1;
            const int r2i = (rb + 2 < kT) ? rb + 2 : kT - 1;
            const int r3i = (rb + 3 < kT) ? rb + 3 : kT - 1;
            const int r4i = (rb + 4 < kT) ? rb + 4 : kT - 1;
            const int r5i = (rb + 5 < kT) ? rb + 5 : kT - 1;
            const int r6i = (rb + 6 < kT) ? rb + 6 : kT - 1;
            const int r7i = (rb + 7 < kT) ? rb + 7 : kT - 1;
            q0 = base[(size_t)r0i * kH]; q1 = base[(size_t)r1i * kH];
            q2 = base[(size_t)r2i * kH]; q3 = base[(size_t)r3i * kH];
            q4 = base[(size_t)r4i * kH]; q5 = base[(size_t)r5i * kH];
            q6 = base[(size_t)r6i * kH]; q7 = base[(size_t)r7i * kH];
        }

        // ---- quarter-dot: 4 chunk-chains of 16 fma (k ascending);
        // coefficients are the exact 0.0/1.0 spike floats (broadcast reads).
        const float* sb = smem + (t & 1) * 256 + qtr * 64;
        float cs[4];
#pragma unroll
        for (int c = 0; c < 4; ++c) {
            const float4 f0 = *reinterpret_cast<const float4*>(sb + c * 16);
            const float4 f1 = *reinterpret_cast<const float4*>(sb + c * 16 + 4);
            const float4 f2 = *reinterpret_cast<const float4*>(sb + c * 16 + 8);
            const float4 f3 = *reinterpret_cast<const float4*>(sb + c * 16 + 12);
            float a = 0.f;
            a = fmaf(f0.x, Vr[c * 16 +  0], a); a = fmaf(f0.y, Vr[c * 16 +  1], a);
            a = fmaf(f0.z, Vr[c * 16 +  2], a); a = fmaf(f0.w, Vr[c * 16 +  3], a);
            a = fmaf(f1.x, Vr[c * 16 +  4], a); a = fmaf(f1.y, Vr[c * 16 +  5], a);
            a = fmaf(f1.z, Vr[c * 16 +  6], a); a = fmaf(f1.w, Vr[c * 16 +  7], a);
            a = fmaf(f2.x, Vr[c * 16 +  8], a); a = fmaf(f2.y, Vr[c * 16 +  9], a);
            a = fmaf(f2.z, Vr[c * 16 + 10], a); a = fmaf(f2.w, Vr[c * 16 + 11], a);
            a = fmaf(f3.x, Vr[c * 16 + 12], a); a = fmaf(f3.y, Vr[c * 16 + 13], a);
            a = fmaf(f3.z, Vr[c * 16 + 14], a); a = fmaf(f3.w, Vr[c * 16 + 15], a);
            cs[c] = a;
        }
        // rq = quarter's node of the verified 16-leaf tree
        const float rq = (cs[0] + cs[1]) + (cs[2] + cs[3]);

        if (qtr != 0) part[(qtr - 1) * 256 + h] = rq;

        __syncthreads();   // barrier A: partials visible

        if (qtr == 0) {
            const float r1v = part[0 * 256 + h];
            const float r2v = part[1 * 256 + h];
            const float r3v = part[2 * 256 + h];
            const float rec = ((rq + r1v) + (r2v + r3v)) + br;  // ((r0+r1)+(r2+r3))+br
            const float p = p0;
            float m2;
            {
#pragma clang fp contract(off)
                const float input_ = p + spk;   // combined = proj + spk
                m2 = kBeta * mem;               // reference op order
                m2 = m2 + input_;
                m2 = m2 + rec;
                m2 = m2 - spk * kThr;           // reset == spk_prev exactly
            }
            const bool fire = (m2 > kThr);
            const float ns = fire ? 1.0f : 0.0f;
            smem[((t & 1) ^ 1) * 256 + h] = ns;   // publish next-step coefficient
            mem = m2;
            spk = ns;

            // shift registers
            if ((t & 7) == 7) {
                p0 = q0; p1 = q1; p2 = q2; p3 = q3;
                p4 = q4; p5 = q5; p6 = q6; p7 = q7;
            } else {
                p0 = p1; p1 = p2; p2 = p3; p3 = p4; p4 = p5; p5 = p6; p6 = p7;
            }
            o0 = o1; o1 = o2; o2 = o3; o3 = o4; o4 = o5; o5 = o6; o6 = o7; o7 = ns;
        }

        __syncthreads();   // barrier B: new spike vector visible
    }

    // final burst of spikes (t = kT-8 .. kT-1)
    if (qtr == 0) {
        float* sg = base + (size_t)(kT - 8) * kH;
        sg[(size_t)0 * kH] = o0; sg[(size_t)1 * kH] = o1;
        sg[(size_t)2 * kH] = o2; sg[(size_t)3 * kH] = o3;
        sg[(size_t)4 * kH] = o4; sg[(size_t)5 * kH] = o5;
        sg[(size_t)6 * kH] = o6; sg[(size_t)7 * kH] = o7;
    }
}

// ---------------------------------------------------------------------------
__global__ void __launch_bounds__(1024, 4)
fused(const float* __restrict__ x, const float* __restrict__ W,
      const float* __restrict__ b_in, const float* __restrict__ V,
      const float* __restrict__ b_rec, float* __restrict__ PO,
      int* flags, int n_scan)
{
    __shared__ __align__(16) float smem[SMEM_FLOATS];
    if ((int)blockIdx.x < n_scan) {
        scan_body(PO, V, b_rec, flags, smem);
    } else {
        gemm_body(x, W, b_in, V == nullptr ? PO : PO, flags, (int)blockIdx.x - n_scan, smem);
    }
}

// ---------------------------------------------------------------------------
extern "C" void kernel_launch(void* const* d_in, const int* in_sizes, int n_in,
                              void* d_out, int out_size, void* d_ws, size_t ws_size,
                              hipStream_t stream) {
    const float* x     = (const float*)d_in[0];
    const float* W_in  = (const float*)d_in[1];
    const float* b_in  = (const float*)d_in[2];
    const float* V     = (const float*)d_in[3];
    const float* b_rec = (const float*)d_in[4];
    float* out = (float*)d_out;

    const size_t flag_bytes = (size_t)N_SCAN * FLAGS_PER_B * sizeof(int);
    if (ws_size >= flag_bytes) {
        int* flags = (int*)d_ws;
        hipMemsetAsync(flags, 0, flag_bytes, stream);   // ws is poisoned 0xAA
        fused<<<N_SCAN + N_GEMM, 1024, 0, stream>>>(x, W_in, b_in, V, b_rec,
                                                    out, flags, N_SCAN);
    } else {
        // fallback: sequential (no flags) — GEMM pass, then scan pass
        fused<<<N_GEMM, 1024, 0, stream>>>(x, W_in, b_in, V, b_rec, out, nullptr, 0);
        fused<<<N_SCAN, 1024, 0, stream>>>(x, W_in, b_in, V, b_rec, out, nullptr, N_SCAN);
    }
}

// Round 5
// 1804.113 us; speedup vs baseline: 11.5877x; 1.1787x over previous
//
#include <hip/hip_runtime.h>
#include <cstddef>
#include <cstdint>

// Problem constants
#define kB 32
#define kT 2048
#define kIn 512
#define kH 256
#define kBeta 0.85f
#define kThr 1.0f

// Fused-kernel layout: blocks [0, N_SCAN) = scan (one per batch),
// blocks [N_SCAN, N_SCAN+N_GEMM) = GEMM tiles (256x256, t-major order).
#define N_SCAN kB
#define N_GEMM (kB * 8)        // 32 b x 8 t_tiles (256 rows each)
#define FLAGS_PER_B 8

// GEMM tile config: 256x256 tile, BK=16, 1024 threads, 8x8 micro-tile.
#define GBM 256
#define GBK 16
#define GLDA 260               // +4 pad: conflict-free transposed staging

// scan smem map (floats)
#define SSTRIDE 260            // pbuf row stride (verbatim R6)
#define SM_PBUF 16             // [16, 16+16*260)   partials
#define SM_PRING (SM_PBUF + 16 * SSTRIDE)   // 4176: proj ring, 16 slots x 256
#define SM_OBUF  (SM_PRING + 16 * 256)      // 8272: spike outbox, 8 slots x 256
#define SMEM_SCAN (SM_OBUF + 8 * 256)       // 10320 floats = 41.3 KB
#define SMEM_GEMM (2 * GBK * GLDA)          // 8320 floats
#define SMEM_FLOATS (SMEM_SCAN > SMEM_GEMM ? SMEM_SCAN : SMEM_GEMM)

__device__ __forceinline__ void wait_flag(int* f) {
    // acquire/agent: later proj loads must see the producer XCD's stores
    while (__hip_atomic_load(f, __ATOMIC_ACQUIRE, __HIP_MEMORY_SCOPE_AGENT) == 0) {
        __builtin_amdgcn_s_sleep(2);
    }
}

// Scan barrier: LDS-fence only (lgkmcnt(0) + raw s_barrier). Unlike
// __syncthreads() this does NOT drain vmcnt, so wave15's proj prefetch
// loads stay in flight across barriers (counted-vmcnt principle). All
// cross-wave scan traffic is LDS, so lgkmcnt(0) is the only fence needed.
__device__ __forceinline__ void scan_bar() {
    asm volatile("s_waitcnt lgkmcnt(0)" ::: "memory");
    __builtin_amdgcn_s_barrier();
}

// ---------------------------------------------------------------------------
// GEMM body: proj tile = x(256xK) @ W_in^T(Kx256) + b_in, then publish flag.
// Verbatim from the verified round-6 kernel (bit-identical proj).
// ---------------------------------------------------------------------------
__device__ void gemm_body(const float* __restrict__ A,
                          const float* __restrict__ W,
                          const float* __restrict__ bias,
                          float* __restrict__ P,
                          int* flags, int gid, float* smem)
{
    float* As = smem;
    float* Bs = smem + GBK * GLDA;
    const int tid = threadIdx.x;
    const int b  = gid & 31;          // t-major tile order: all b at t_tile 0 first
    const int tt = gid >> 5;          // 0..7
    const int bm = b * kT + tt * GBM; // row offset in flattened (B*T)
    const int tx = tid & 31;
    const int ty = tid >> 5;          // 0..31

    float acc[8][8];
#pragma unroll
    for (int i = 0; i < 8; ++i)
#pragma unroll
        for (int j = 0; j < 8; ++j) acc[i][j] = 0.f;

    const int r = tid >> 2, kc = (tid & 3) << 2;

    for (int kb = 0; kb < kIn; kb += GBK) {
        const float4 av = *reinterpret_cast<const float4*>(A + (size_t)(bm + r) * kIn + kb + kc);
        const float4 bv = *reinterpret_cast<const float4*>(W + (size_t)r * kIn + kb + kc);
        __syncthreads();   // previous iteration's LDS reads done
        As[(kc + 0) * GLDA + r] = av.x;
        As[(kc + 1) * GLDA + r] = av.y;
        As[(kc + 2) * GLDA + r] = av.z;
        As[(kc + 3) * GLDA + r] = av.w;
        Bs[(kc + 0) * GLDA + r] = bv.x;
        Bs[(kc + 1) * GLDA + r] = bv.y;
        Bs[(kc + 2) * GLDA + r] = bv.z;
        Bs[(kc + 3) * GLDA + r] = bv.w;
        __syncthreads();

#pragma unroll
        for (int k = 0; k < GBK; ++k) {
            const float4 aa0 = *reinterpret_cast<const float4*>(&As[k * GLDA + ty * 4]);
            const float4 aa1 = *reinterpret_cast<const float4*>(&As[k * GLDA + ty * 4 + 128]);
            const float4 bb0 = *reinterpret_cast<const float4*>(&Bs[k * GLDA + tx * 4]);
            const float4 bb1 = *reinterpret_cast<const float4*>(&Bs[k * GLDA + tx * 4 + 128]);
            const float av8[8] = {aa0.x, aa0.y, aa0.z, aa0.w, aa1.x, aa1.y, aa1.z, aa1.w};
            const float bv8[8] = {bb0.x, bb0.y, bb0.z, bb0.w, bb1.x, bb1.y, bb1.z, bb1.w};
#pragma unroll
            for (int i = 0; i < 8; ++i)
#pragma unroll
                for (int j = 0; j < 8; ++j)
                    acc[i][j] = fmaf(av8[i], bv8[j], acc[i][j]);
        }
    }

    const float4 bl = *reinterpret_cast<const float4*>(bias + tx * 4);
    const float4 bh = *reinterpret_cast<const float4*>(bias + tx * 4 + 128);
#pragma unroll
    for (int i = 0; i < 8; ++i) {
        const int m = bm + ty * 4 + (i & 3) + ((i >> 2) << 7);
        float4 o0, o1;
        o0.x = acc[i][0] + bl.x; o0.y = acc[i][1] + bl.y;
        o0.z = acc[i][2] + bl.z; o0.w = acc[i][3] + bl.w;
        o1.x = acc[i][4] + bh.x; o1.y = acc[i][5] + bh.y;
        o1.z = acc[i][6] + bh.z; o1.w = acc[i][7] + bh.w;
        *reinterpret_cast<float4*>(P + (size_t)m * kH + tx * 4) = o0;
        *reinterpret_cast<float4*>(P + (size_t)m * kH + tx * 4 + 128) = o1;
    }

    __syncthreads();   // all stores executed block-wide
    if (flags && tid == 0) {
        __threadfence();                                  // device-scope release
        atomicAdd(flags + b * FLAGS_PER_B + tt, 1);       // publish (b, tt) ready
    }
}

// ---------------------------------------------------------------------------
// Scan, round 11: R6's verified 16-wave structure (mask exchange, nibble-skip
// expansion, pbuf[w][h] partials, 16-leaf tree, contract-off update: all
// VERBATIM -> bit-identical output) with the vmem subsystem restructured:
//   - wave 15 prefetches proj rows into a 16-slot LDS ring (pring); owners
//     get p via one ds_read_b32 issued at step-top (latency hidden).
//   - wave 14 drains spikes from an 8-slot LDS outbox (obuf) that owners
//     fill in phase 2, storing to global in 8-row bursts.
//   - scan barriers are lgkmcnt(0)+s_barrier (no vmcnt drain), so wave15's
//     burst loads stay outstanding across barriers; they are consumed 2
//     steps (~2800 cyc) after issue -> zero stall. Owner waves carry zero
//     vmem, so every barrier is clean for them.
// Ring slot discipline: owners read slots (8tb&15)+ti; wave15 writes the
// opposite 8-slot half (rows 8tb+8..+15 -> slots (8tb+8)&15) -> disjoint.
// Outbox: wave14 reads slots 0..7 (rows of tb-1) before barrier A of ti=0;
// owners rewrite slot ti only after barrier A -> ordered.
// ---------------------------------------------------------------------------
__device__ void scan_body(float* __restrict__ PO,
                          const float* __restrict__ V,
                          const float* __restrict__ brec,
                          int* flags, float* smem)
{
    unsigned long long* smask = reinterpret_cast<unsigned long long*>(smem);
    float* pbuf  = smem + SM_PBUF;
    float* pring = smem + SM_PRING;
    float* obuf  = smem + SM_OBUF;

    const int b = blockIdx.x;
    const int tid = threadIdx.x;
    const int w = tid >> 6;         // wave 0..15 = k-chunk index
    const int l = tid & 63;
    const int h0 = l << 2;          // this thread's 4 h-rows: h0..h0+3
    const int kc = w << 4;          // k base
    const bool owner = (tid < kH);  // waves 0-3: per-neuron state owners
    const int h = tid & (kH - 1);

    // V regs: Vr[i][c] = V[h0+i][kc+c]   (64 VGPRs, one-time load; verbatim R6)
    float Vr[4][16];
#pragma unroll
    for (int i = 0; i < 4; ++i) {
        const float4* vp = reinterpret_cast<const float4*>(V + (size_t)(h0 + i) * kH + kc);
#pragma unroll
        for (int c4 = 0; c4 < 4; ++c4) {
            const float4 v = vp[c4];
            Vr[i][c4 * 4 + 0] = v.x; Vr[i][c4 * 4 + 1] = v.y;
            Vr[i][c4 * 4 + 2] = v.z; Vr[i][c4 * 4 + 3] = v.w;
        }
    }

    const float br = owner ? brec[h] : 0.f;
    float mem = 0.f, spk = 0.f;
    float* po_b = PO + (size_t)b * (size_t)kT * kH;

    if (tid < 4) smask[tid] = 0ull;

    int* bflags = flags ? (flags + b * FLAGS_PER_B) : nullptr;

    // init: wave 15 fills ring slots 0..7 with proj rows 0..7
    if (w == 15) {
        if (bflags) wait_flag(bflags + 0);     // proj tile (b, t<256) ready
#pragma unroll
        for (int r = 0; r < 8; ++r) {
            const float4 v = *reinterpret_cast<const float4*>(po_b + (size_t)r * kH + 4 * l);
            *reinterpret_cast<float4*>(pring + r * 256 + 4 * l) = v;
        }
    }
    scan_bar();

    const int mshift = (w & 3) << 4;           // 16-bit sub-chunk of the u64

    for (int tb = 0; tb < kT / 8; ++tb) {
        float4 g0, g1, g2, g3, g4, g5, g6, g7;   // wave15 staging (per-tb lifetime)
#pragma unroll
        for (int ti = 0; ti < 8; ++ti) {
            const int t = tb * 8 + ti;

            if (ti == 0) {
                // wave 15: issue next-burst proj loads (rows 8tb+8..+15);
                // left in flight until ti==2 (no barrier drains them).
                if (w == 15 && tb < kT / 8 - 1) {
                    if (bflags && ((tb + 1) & 31) == 0 && ((tb + 1) >> 5) < 8)
                        wait_flag(bflags + ((tb + 1) >> 5));
                    const size_t r0 = (size_t)(tb * 8 + 8) * kH + 4 * l;
                    g0 = *reinterpret_cast<const float4*>(po_b + r0 + 0 * kH);
                    g1 = *reinterpret_cast<const float4*>(po_b + r0 + 1 * kH);
                    g2 = *reinterpret_cast<const float4*>(po_b + r0 + 2 * kH);
                    g3 = *reinterpret_cast<const float4*>(po_b + r0 + 3 * kH);
                    g4 = *reinterpret_cast<const float4*>(po_b + r0 + 4 * kH);
                    g5 = *reinterpret_cast<const float4*>(po_b + r0 + 5 * kH);
                    g6 = *reinterpret_cast<const float4*>(po_b + r0 + 6 * kH);
                    g7 = *reinterpret_cast<const float4*>(po_b + r0 + 7 * kH);
                }
                // wave 14: drain previous burst's spikes obuf -> global
                if (w == 14 && tb > 0) {
#pragma unroll
                    for (int r = 0; r < 8; ++r) {
                        const float4 v = *reinterpret_cast<const float4*>(obuf + r * 256 + 4 * l);
                        *reinterpret_cast<float4*>(po_b + (size_t)((tb - 1) * 8 + r) * kH + 4 * l) = v;
                    }
                }
            }
            if (ti == 2 && w == 15 && tb < kT / 8 - 1) {
                // write staged rows into the opposite ring half
                const int s0 = (tb & 1) ? 0 : 8;   // (8tb+8) & 15
                *reinterpret_cast<float4*>(pring + (s0 + 0) * 256 + 4 * l) = g0;
                *reinterpret_cast<float4*>(pring + (s0 + 1) * 256 + 4 * l) = g1;
                *reinterpret_cast<float4*>(pring + (s0 + 2) * 256 + 4 * l) = g2;
                *reinterpret_cast<float4*>(pring + (s0 + 3) * 256 + 4 * l) = g3;
                *reinterpret_cast<float4*>(pring + (s0 + 4) * 256 + 4 * l) = g4;
                *reinterpret_cast<float4*>(pring + (s0 + 5) * 256 + 4 * l) = g5;
                *reinterpret_cast<float4*>(pring + (s0 + 6) * 256 + 4 * l) = g6;
                *reinterpret_cast<float4*>(pring + (s0 + 7) * 256 + 4 * l) = g7;
            }

            // owner: early proj read (consumed after barrier A -> latency hidden)
            float pld = 0.f;
            if (owner) pld = pring[(t & 15) * 256 + h];

            // ---- phase 1 (verbatim R6): partial dots from 16 mask bits
            const unsigned long long m = smask[w >> 2];
            const uint32_t chunk =
                __builtin_amdgcn_readfirstlane((uint32_t)(m >> mshift)) & 0xFFFFu;

            float a0 = 0.f, a1 = 0.f, a2 = 0.f, a3 = 0.f;
#pragma unroll
            for (int n = 0; n < 4; ++n) {
                const uint32_t nib = (chunk >> (n * 4)) & 0xFu;
                if (nib) {                       // scalar (wave-uniform) skip
#pragma unroll
                    for (int bit = 0; bit < 4; ++bit) {
                        const int j = n * 4 + bit;
                        const float bf = (float)((nib >> bit) & 1u);  // 1 cvt
                        a0 = fmaf(bf, Vr[0][j], a0);                  // 4 fmacs
                        a1 = fmaf(bf, Vr[1][j], a1);
                        a2 = fmaf(bf, Vr[2][j], a2);
                        a3 = fmaf(bf, Vr[3][j], a3);
                    }
                }
            }
            float4 part; part.x = a0; part.y = a1; part.z = a2; part.w = a3;
            *reinterpret_cast<float4*>(pbuf + w * SSTRIDE + h0) = part;

            scan_bar();   // barrier A: partials visible

            // ---- phase 2 (owner waves): 16-way reduce + membrane update
            if (owner) {
                float s0  = pbuf[ 0 * SSTRIDE + h], s1  = pbuf[ 1 * SSTRIDE + h];
                float s2  = pbuf[ 2 * SSTRIDE + h], s3  = pbuf[ 3 * SSTRIDE + h];
                float s4  = pbuf[ 4 * SSTRIDE + h], s5  = pbuf[ 5 * SSTRIDE + h];
                float s6  = pbuf[ 6 * SSTRIDE + h], s7  = pbuf[ 7 * SSTRIDE + h];
                float s8  = pbuf[ 8 * SSTRIDE + h], s9  = pbuf[ 9 * SSTRIDE + h];
                float s10 = pbuf[10 * SSTRIDE + h], s11 = pbuf[11 * SSTRIDE + h];
                float s12 = pbuf[12 * SSTRIDE + h], s13 = pbuf[13 * SSTRIDE + h];
                float s14 = pbuf[14 * SSTRIDE + h], s15 = pbuf[15 * SSTRIDE + h];
                const float r0 = (s0 + s1) + (s2 + s3);
                const float r1 = (s4 + s5) + (s6 + s7);
                const float r2 = (s8 + s9) + (s10 + s11);
                const float r3 = (s12 + s13) + (s14 + s15);
                const float rec = ((r0 + r1) + (r2 + r3)) + br;
                const float p = pld;
                float m2;
                {
#pragma clang fp contract(off)
                    const float input_ = p + spk;   // combined = proj + spk
                    m2 = kBeta * mem;               // reference op order
                    m2 = m2 + input_;
                    m2 = m2 + rec;
                    m2 = m2 - spk * kThr;           // reset == spk_prev exactly
                }
                const bool fire = (m2 > kThr);
                const float ns = fire ? 1.0f : 0.0f;
                const unsigned long long bm = __ballot(fire);
                if ((tid & 63) == 0) smask[tid >> 6] = bm;
                obuf[ti * 256 + h] = ns;            // outbox for wave 14
                mem = m2;
                spk = ns;
            }

            scan_bar();   // barrier B: new mask + outbox slot visible
        }
    }

    // final burst: rows 2040..2047 from the outbox
    if (w == 14) {
#pragma unroll
        for (int r = 0; r < 8; ++r) {
            const float4 v = *reinterpret_cast<const float4*>(obuf + r * 256 + 4 * l);
            *reinterpret_cast<float4*>(po_b + (size_t)((kT / 8 - 1) * 8 + r) * kH + 4 * l) = v;
        }
    }
}

// ---------------------------------------------------------------------------
__global__ void __launch_bounds__(1024, 4)
fused(const float* __restrict__ x, const float* __restrict__ W,
      const float* __restrict__ b_in, const float* __restrict__ V,
      const float* __restrict__ b_rec, float* __restrict__ PO,
      int* flags, int n_scan)
{
    __shared__ __align__(16) float smem[SMEM_FLOATS];
    if ((int)blockIdx.x < n_scan) {
        scan_body(PO, V, b_rec, flags, smem);
    } else {
        gemm_body(x, W, b_in, PO, flags, (int)blockIdx.x - n_scan, smem);
    }
}

// ---------------------------------------------------------------------------
extern "C" void kernel_launch(void* const* d_in, const int* in_sizes, int n_in,
                              void* d_out, int out_size, void* d_ws, size_t ws_size,
                              hipStream_t stream) {
    const float* x     = (const float*)d_in[0];
    const float* W_in  = (const float*)d_in[1];
    const float* b_in  = (const float*)d_in[2];
    const float* V     = (const float*)d_in[3];
    const float* b_rec = (const float*)d_in[4];
    float* out = (float*)d_out;

    const size_t flag_bytes = (size_t)N_SCAN * FLAGS_PER_B * sizeof(int);
    if (ws_size >= flag_bytes) {
        int* flags = (int*)d_ws;
        hipMemsetAsync(flags, 0, flag_bytes, stream);   // ws is poisoned 0xAA
        fused<<<N_SCAN + N_GEMM, 1024, 0, stream>>>(x, W_in, b_in, V, b_rec,
                                                    out, flags, N_SCAN);
    } else {
        // fallback: sequential (no flags) — GEMM pass, then scan pass
        fused<<<N_GEMM, 1024, 0, stream>>>(x, W_in, b_in, V, b_rec, out, nullptr, 0);
        fused<<<N_SCAN, 1024, 0, stream>>>(x, W_in, b_in, V, b_rec, out, nullptr, N_SCAN);
    }
}